// Round 4
// baseline (210.659 us; speedup 1.0000x reference)
//
#include <hip/hip_runtime.h>
#include <math.h>

#define BB 64
#define SS 2048
#define HH 1024
#define NS 128    // number of s-chunks
#define SC 16     // s-rows per chunk (NS*SC = SS)

typedef float f4 __attribute__((ext_vector_type(4)));

// ws layout (floats):
#define Q_OFF    0
#define PCTX_OFF (BB * HH)                      // part_ctx [64][NS][1024]
#define PML_OFF  (PCTX_OFF + BB * NS * HH)      // part_ml  [64][NS][2]
#define CTXF_OFF (PML_OFF + BB * NS * 2)        // ctx_final[64][1024]
// total ~= 34.1 MB

// ---------------------------------------------------------------------------
// R1 gemm64 (verbatim): out[b][i] = act( sum_j A(b,j) * W[i*K + j] )
// ---------------------------------------------------------------------------
__global__ __launch_bounds__(256) void gemm64(
    const float* __restrict__ A0, const float* __restrict__ A1,
    const float* __restrict__ W, float* __restrict__ out,
    int nchunks, int do_tanh)
{
    __shared__ float A_lds[64 * 256];
    __shared__ float W_lds[4 * 256];
    const int t  = threadIdx.x;
    const int it = blockIdx.x;
    const int b  = t & 63;
    const int il = t >> 6;
    const int K  = nchunks << 8;
    float acc = 0.f;

    for (int kc = 0; kc < nchunks; ++kc) {
        for (int idx = t; idx < 64 * 64; idx += 256) {
            const int row = idx >> 6;
            const int g   = idx & 63;
            const float* src = (kc < 4) ? (A0 + row * 1024 + kc * 256)
                                        : (A1 + row * 1024 + (kc - 4) * 256);
            float4 v = *(const float4*)(src + g * 4);
            ((float4*)A_lds)[row * 64 + (g ^ row)] = v;
        }
        for (int idx = t; idx < 1024; idx += 256) {
            const int r2 = idx >> 8;
            const int cc = idx & 255;
            W_lds[idx] = W[(size_t)(it * 4 + r2) * K + kc * 256 + cc];
        }
        __syncthreads();
        #pragma unroll 8
        for (int j4 = 0; j4 < 64; ++j4) {
            float4 a  = ((const float4*)A_lds)[b * 64 + (j4 ^ b)];
            float4 wv = ((const float4*)W_lds)[il * 64 + j4];
            acc += a.x * wv.x + a.y * wv.y + a.z * wv.z + a.w * wv.w;
        }
        __syncthreads();
    }
    if (do_tanh) acc = tanhf(acc);
    out[b * 1024 + it * 4 + il] = acc;
}

// ---------------------------------------------------------------------------
// attn_row: wave = one b. Block (bg, n) = 8 waves covering b = bg*8..bg*8+7,
// s = n*SC .. n*SC+SC-1. The 8 waves read ADJACENT 4 KB rows -> 32 KB
// contiguous per s; blocks sharing n (bg = fastest grid dim) cover the full
// 256 KB s-row. Everything in registers: no LDS, no barriers.
// Depth-1 register prefetch; branchless online softmax.
// ---------------------------------------------------------------------------
__global__ __launch_bounds__(512) void attn_row(
    const float* __restrict__ enc, const float* __restrict__ q,
    float* __restrict__ part_ctx, float* __restrict__ part_ml,
    float* __restrict__ scores_raw)
{
    const int t    = threadIdx.x;
    const int w    = t >> 6;
    const int lane = t & 63;
    const int bg   = blockIdx.x;       // 0..7
    const int n    = blockIdx.y;       // 0..NS-1
    const int b    = bg * 8 + w;
    const int s0   = n * SC;

    // q fragment in registers
    f4 qreg[4];
    #pragma unroll
    for (int k = 0; k < 4; ++k)
        qreg[k] = *(const f4*)(q + (size_t)b * HH + k * 256 + 4 * lane);

    const size_t RS = (size_t)BB * HH;  // floats between s and s+1
    const float* rp = enc + ((size_t)s0 * BB + b) * HH + 4 * lane;

    f4 cur[4], nxt[4];
    #pragma unroll
    for (int k = 0; k < 4; ++k)
        cur[k] = __builtin_nontemporal_load((const f4*)(rp + k * 256));

    float m = -INFINITY, lsum = 0.f;
    f4 ctxv[4];
    #pragma unroll
    for (int k = 0; k < 4; ++k) ctxv[k] = (f4)0.f;

    for (int i = 0; i < SC; ++i) {
        if (i + 1 < SC) {
            const float* np = rp + RS;
            #pragma unroll
            for (int k = 0; k < 4; ++k)
                nxt[k] = __builtin_nontemporal_load((const f4*)(np + k * 256));
        }
        // dot(enc_row, q)
        f4 sv = cur[0] * qreg[0];
        sv += cur[1] * qreg[1];
        sv += cur[2] * qreg[2];
        sv += cur[3] * qreg[3];
        float d = sv.x + sv.y + sv.z + sv.w;
        #pragma unroll
        for (int off = 32; off; off >>= 1)
            d += __shfl_xor(d, off, 64);

        if (lane == 0) scores_raw[b * SS + s0 + i] = d;

        // branchless online softmax
        const float nm = fmaxf(m, d);
        const float e  = expf(m - nm);   // 0 on first iter, 1 if no new max
        const float p  = expf(d - nm);
        lsum = lsum * e + p;
        m = nm;
        #pragma unroll
        for (int k = 0; k < 4; ++k)
            ctxv[k] = ctxv[k] * e + p * cur[k];

        if (i + 1 < SC) {
            #pragma unroll
            for (int k = 0; k < 4; ++k) cur[k] = nxt[k];
            rp += RS;
        }
    }

    float* pc = part_ctx + ((size_t)b * NS + n) * HH + 4 * lane;
    #pragma unroll
    for (int k = 0; k < 4; ++k)
        *(f4*)(pc + k * 256) = ctxv[k];
    if (lane == 0) {
        part_ml[(b * NS + n) * 2 + 0] = m;
        part_ml[(b * NS + n) * 2 + 1] = lsum;
    }
}

// ---------------------------------------------------------------------------
// Combine NS partials per b -> ctx_final; normalize weights in place.
// grid = B, 256 threads.
// ---------------------------------------------------------------------------
__global__ __launch_bounds__(256) void attn_combine(
    const float* __restrict__ part_ctx, const float* __restrict__ part_ml,
    float* __restrict__ ctx_final, float* __restrict__ wts)
{
    const int b = blockIdx.x;
    const int t = threadIdx.x;
    __shared__ float mls[NS * 2];
    __shared__ float fs[NS];
    if (t < NS * 2) mls[t] = part_ml[b * NS * 2 + t];
    __syncthreads();

    float M = -INFINITY;
    #pragma unroll 8
    for (int c = 0; c < NS; ++c) M = fmaxf(M, mls[2 * c]);
    if (t < NS) fs[t] = expf(mls[2 * t] - M);
    __syncthreads();

    float L = 0.f;
    #pragma unroll 8
    for (int c = 0; c < NS; ++c) L += fs[c] * mls[2 * c + 1];
    const float inv = 1.0f / L;

    f4 acc = (f4)0.f;
    #pragma unroll 4
    for (int c = 0; c < NS; ++c) {
        const f4 v = *(const f4*)(part_ctx + ((size_t)b * NS + c) * HH + 4 * t);
        acc += fs[c] * v;
    }
    *(f4*)(ctx_final + (size_t)b * HH + 4 * t) = acc * inv;

    #pragma unroll
    for (int s = t; s < SS; s += 256)
        wts[b * SS + s] = expf(wts[b * SS + s] - M) * inv;
}

extern "C" void kernel_launch(void* const* d_in, const int* in_sizes, int n_in,
                              void* d_out, int out_size, void* d_ws, size_t ws_size,
                              hipStream_t stream)
{
    const float* dec   = (const float*)d_in[0];  // [B,H]
    const float* enc   = (const float*)d_in[1];  // [S,B,H]
    const float* W_a   = (const float*)d_in[2];  // [H,H]
    const float* W_out = (const float*)d_in[3];  // [H,2H]
    float* out = (float*)d_out;                  // [B*H] context, then [B*S] weights
    float* ws  = (float*)d_ws;

    float* q         = ws + Q_OFF;
    float* part_ctx  = ws + PCTX_OFF;
    float* part_ml   = ws + PML_OFF;
    float* ctx_final = ws + CTXF_OFF;
    float* wts       = out + BB * HH;

    // 1) q = dec @ W_a^T
    gemm64<<<256, 256, 0, stream>>>(dec, dec, W_a, q, 4, 0);
    // 2) one-pass scores + online-softmax partial context (contiguous streams)
    attn_row<<<dim3(8, NS), 512, 0, stream>>>(enc, q, part_ctx, part_ml, wts);
    // 3) combine partials, normalize weights in place
    attn_combine<<<BB, 256, 0, stream>>>(part_ctx, part_ml, ctx_final, wts);
    // 4) out = tanh(concat(ctx, dec) @ W_out^T)
    gemm64<<<256, 256, 0, stream>>>(ctx_final, dec, W_out, out, 8, 1);
}